// Round 1
// baseline (1054.212 us; speedup 1.0000x reference)
//
#include <hip/hip_runtime.h>
#include <hip/hip_bf16.h>

#define NNODES 200000
#define NEDGES 6400000
#define NFEAT  128
#define NH     16
#define NMLP   100
#define NCLS   27
#define NGRAPH 4096

// ---------------------------------------------------------------------------
// Kernel 1: deg[i] = 1.0f (self-loop)
__global__ __launch_bounds__(256) void k_init_deg(float* __restrict__ deg) {
    int i = blockIdx.x * 256 + threadIdx.x;
    if (i < NNODES) deg[i] = 1.0f;
}

// Kernel 2: deg[dst[e]] += 1
__global__ __launch_bounds__(256) void k_count(const int* __restrict__ dst,
                                               float* __restrict__ deg) {
    int e = blockIdx.x * 256 + threadIdx.x;
    if (e < NEDGES) atomicAdd(&deg[dst[e]], 1.0f);
}

// Kernel 3: A[i] = B[i] = dinv[i] * (x[i] @ W1)   (per-thread row GEMM, W1 in LDS)
__global__ __launch_bounds__(256) void k_gemm1(const float* __restrict__ x,
                                               const float* __restrict__ W1,
                                               const float* __restrict__ deg,
                                               float* __restrict__ A,
                                               float* __restrict__ B) {
    __shared__ float Wsf[NFEAT * NH];     // 8 KB
    int tid = threadIdx.x;
    const float4* Wg = (const float4*)W1;
    float4* Wl = (float4*)Wsf;
    #pragma unroll
    for (int t = 0; t < (NFEAT * NH / 4) / 256; ++t)   // 512 float4 / 256 thr = 2
        Wl[tid + t * 256] = Wg[tid + t * 256];
    __syncthreads();

    int i = blockIdx.x * 256 + tid;
    if (i >= NNODES) return;

    const float4* xr = (const float4*)(x + (size_t)i * NFEAT);
    float acc[NH];
    #pragma unroll
    for (int j = 0; j < NH; ++j) acc[j] = 0.f;

    for (int kk = 0; kk < NFEAT / 4; ++kk) {
        float4 xv = xr[kk];
        #pragma unroll
        for (int t = 0; t < 4; ++t) {
            float xs = (t == 0) ? xv.x : (t == 1) ? xv.y : (t == 2) ? xv.z : xv.w;
            const float* wrow = &Wsf[(kk * 4 + t) * NH];
            #pragma unroll
            for (int j = 0; j < NH; ++j) acc[j] += xs * wrow[j];
        }
    }

    float s = rsqrtf(deg[i]);
    float4* Ar = (float4*)(A + (size_t)i * NH);
    float4* Br = (float4*)(B + (size_t)i * NH);
    #pragma unroll
    for (int q = 0; q < 4; ++q) {
        float4 v = make_float4(acc[q * 4 + 0] * s, acc[q * 4 + 1] * s,
                               acc[q * 4 + 2] * s, acc[q * 4 + 3] * s);
        Ar[q] = v;
        Br[q] = v;
    }
}

// Kernel 4/6: B[dst] += A[src]  (16 lanes per edge, float atomics)
__global__ __launch_bounds__(256) void k_scatter(const int* __restrict__ src,
                                                 const int* __restrict__ dst,
                                                 const float* __restrict__ A,
                                                 float* __restrict__ B) {
    int t = blockIdx.x * 256 + threadIdx.x;
    int e = t >> 4;
    int j = t & 15;
    if (e < NEDGES) {
        int s = src[e];
        int d = dst[e];
        atomicAdd(&B[(size_t)d * NH + j], A[(size_t)s * NH + j]);
    }
}

// Kernel 5: h = relu(dinv*B + b1); A = B = dinv * (h @ W2)
__global__ __launch_bounds__(256) void k_mid(const float* __restrict__ W2,
                                             const float* __restrict__ b1,
                                             const float* __restrict__ deg,
                                             float* __restrict__ A,
                                             float* __restrict__ B) {
    __shared__ float Ws[NH * NH];
    __shared__ float bs[NH];
    int tid = threadIdx.x;
    if (tid < NH * NH) Ws[tid] = W2[tid];
    if (tid < NH) bs[tid] = b1[tid];
    __syncthreads();

    int i = blockIdx.x * 256 + tid;
    if (i >= NNODES) return;

    float s = rsqrtf(deg[i]);
    float h[NH];
    float4* Br = (float4*)(B + (size_t)i * NH);
    #pragma unroll
    for (int q = 0; q < 4; ++q) {
        float4 v = Br[q];
        h[q * 4 + 0] = v.x; h[q * 4 + 1] = v.y; h[q * 4 + 2] = v.z; h[q * 4 + 3] = v.w;
    }
    #pragma unroll
    for (int j = 0; j < NH; ++j) h[j] = fmaxf(h[j] * s + bs[j], 0.f);

    float o[NH];
    #pragma unroll
    for (int j = 0; j < NH; ++j) o[j] = 0.f;
    #pragma unroll
    for (int k = 0; k < NH; ++k) {
        float hk = h[k];
        const float* wrow = &Ws[k * NH];
        #pragma unroll
        for (int j = 0; j < NH; ++j) o[j] += hk * wrow[j];
    }

    float4* Ar = (float4*)(A + (size_t)i * NH);
    #pragma unroll
    for (int q = 0; q < 4; ++q) {
        float4 v = make_float4(o[q * 4 + 0] * s, o[q * 4 + 1] * s,
                               o[q * 4 + 2] * s, o[q * 4 + 3] * s);
        Ar[q] = v;
        Br[q] = v;
    }
}

// Kernel 7: per-graph block: pool (sorted batch -> binary search bounds),
// relu, MLP1(16->100), relu, MLP2(100->27)
__global__ __launch_bounds__(256) void k_pool(const float* __restrict__ B,
                                              const float* __restrict__ deg,
                                              const int* __restrict__ batch,
                                              const float* __restrict__ b2,
                                              const float* __restrict__ Wl1,
                                              const float* __restrict__ bl1,
                                              const float* __restrict__ Wl2,
                                              const float* __restrict__ bl2,
                                              float* __restrict__ out) {
    __shared__ int   seg[2];
    __shared__ float bs2[NH];
    __shared__ float red[16][17];
    __shared__ float gv[NH];
    __shared__ float g1[NMLP];

    int g   = blockIdx.x;
    int tid = threadIdx.x;

    if (tid < NH) bs2[tid] = b2[tid];
    if (tid == 0) {
        int lo = 0, hi = NNODES;
        while (lo < hi) { int m = (lo + hi) >> 1; if (batch[m] < g) lo = m + 1; else hi = m; }
        seg[0] = lo;
        int lo2 = lo; hi = NNODES;
        while (lo2 < hi) { int m = (lo2 + hi) >> 1; if (batch[m] < g + 1) lo2 = m + 1; else hi = m; }
        seg[1] = lo2;
    }
    __syncthreads();

    int start = seg[0], end = seg[1];
    int nl = tid >> 4, j = tid & 15;

    float p = 0.f;
    for (int i = start + nl; i < end; i += 16)
        p += B[(size_t)i * NH + j] * rsqrtf(deg[i]) + bs2[j];
    red[nl][j] = p;
    __syncthreads();

    if (nl == 0) {
        float ssum = 0.f;
        #pragma unroll
        for (int n = 0; n < 16; ++n) ssum += red[n][j];
        gv[j] = fmaxf(ssum, 0.f);
    }
    __syncthreads();

    if (tid < NMLP) {
        float a = bl1[tid];
        #pragma unroll
        for (int k = 0; k < NH; ++k) a += gv[k] * Wl1[k * NMLP + tid];
        g1[tid] = fmaxf(a, 0.f);
    }
    __syncthreads();

    if (tid < NCLS) {
        float a = bl2[tid];
        for (int k = 0; k < NMLP; ++k) a += g1[k] * Wl2[k * NCLS + tid];
        out[(size_t)g * NCLS + tid] = a;
    }
}

// ---------------------------------------------------------------------------
extern "C" void kernel_launch(void* const* d_in, const int* in_sizes, int n_in,
                              void* d_out, int out_size, void* d_ws, size_t ws_size,
                              hipStream_t stream) {
    const float* x     = (const float*)d_in[0];
    const int*   edge  = (const int*)d_in[1];   // [2, E] flat: src then dst
    const int*   batch = (const int*)d_in[2];
    const float* W1    = (const float*)d_in[3];
    const float* b1    = (const float*)d_in[4];
    const float* W2    = (const float*)d_in[5];
    const float* b2    = (const float*)d_in[6];
    const float* Wl1   = (const float*)d_in[7];
    const float* bl1   = (const float*)d_in[8];
    const float* Wl2   = (const float*)d_in[9];
    const float* bl2   = (const float*)d_in[10];
    float*       out   = (float*)d_out;

    char* ws = (char*)d_ws;
    float* deg = (float*)ws;                                   // N floats (800000 B)
    float* A   = (float*)(ws + (size_t)NNODES * 4);            // N*16 floats
    float* B   = A + (size_t)NNODES * NH;                      // N*16 floats

    const int* src = edge;
    const int* dst = edge + NEDGES;

    int nb_nodes = (NNODES + 255) / 256;
    int nb_edges = (NEDGES + 255) / 256;
    int nb_scat  = (NEDGES * 16) / 256;   // exact: 102.4M / 256

    k_init_deg<<<nb_nodes, 256, 0, stream>>>(deg);
    k_count<<<nb_edges, 256, 0, stream>>>(dst, deg);
    k_gemm1<<<nb_nodes, 256, 0, stream>>>(x, W1, deg, A, B);
    k_scatter<<<nb_scat, 256, 0, stream>>>(src, dst, A, B);
    k_mid<<<nb_nodes, 256, 0, stream>>>(W2, b1, deg, A, B);
    k_scatter<<<nb_scat, 256, 0, stream>>>(src, dst, A, B);
    k_pool<<<NGRAPH, 256, 0, stream>>>(B, deg, batch, b2, Wl1, bl1, Wl2, bl2, out);
}